// Round 3
// baseline (204.118 us; speedup 1.0000x reference)
//
#include <hip/hip_runtime.h>
#include <cstdint>
#include <cstddef>

#define GNPB 8        // nodes per gather block (8 waves, 1 node/wave)
#define MNPB 16       // rows per gemm block
#define GAST 264      // gemm LDS A row stride in elems (528 B) — breaks 512B-stride banks
#define VP_BLOCKS 16  // prep blocks packing Vp (4096 threads, K=256)

typedef __attribute__((ext_vector_type(8))) short bf16x8;
typedef __attribute__((ext_vector_type(4))) float f32x4;

static __device__ __forceinline__ unsigned short f2bf(float f) {
    unsigned int u = __builtin_bit_cast(unsigned int, f);
    u += 0x7fffu + ((u >> 16) & 1u);
    return (unsigned short)(u >> 16);
}
static __device__ __forceinline__ float bfhi(unsigned int u) { return __builtin_bit_cast(float, u & 0xFFFF0000u); }
static __device__ __forceinline__ float bflo(unsigned int u) { return __builtin_bit_cast(float, u << 16); }
// masked bf16x8 accumulate: m = all-ones keeps, 0 zeroes (bf16 0x0000 == +0.0)
static __device__ __forceinline__ void acc8(float* a, const uint4& v, unsigned m) {
    unsigned x0 = v.x & m, x1 = v.y & m, x2 = v.z & m, x3 = v.w & m;
    a[0] += bflo(x0); a[1] += bfhi(x0); a[2] += bflo(x1); a[3] += bfhi(x1);
    a[4] += bflo(x2); a[5] += bfhi(x2); a[6] += bflo(x3); a[7] += bfhi(x3);
}

// ---------------- Prep: Vp pack (B = [Wg+Ws | Wl], K=256), xb = bf16(x), blkoff ----------------
// Vp layout: element ((g*8 + s)*64 + lane)*8 + j = B1[g*16 + (lane&15)][s*32 + (lane>>4)*8 + j]
// so a wave's B-fragment load for (col-group g, kstep s) is ONE contiguous 1KB read.
__global__ __launch_bounds__(256)
void prep(const float* __restrict__ x, const float* __restrict__ Wg,
          const float* __restrict__ Wl, const float* __restrict__ Ws,
          const int* __restrict__ dst, unsigned short* __restrict__ Vp,
          unsigned short* __restrict__ xb, int* __restrict__ blkoff,
          int total8, int nblk_g, int noffb, int E) {
    const int bx = blockIdx.x, t = threadIdx.x;
    if (bx < VP_BLOCKS) {
        int gid = bx * 256 + t;
        if (gid < 4096) {
            int l = gid & 63, srow = (gid >> 6) & 7, g = gid >> 9;
            int o = g * 16 + (l & 15);
            int k = srow * 32 + (l >> 4) * 8;
            uint4 u;
            if (k < 128) {                     // first K-segment: W1 = Wg + Ws (fold verified R1)
                const float* pg = Wg + o * 128 + k;
                const float* ps = Ws + o * 128 + k;
                u.x = (unsigned)f2bf(pg[0]+ps[0]) | ((unsigned)f2bf(pg[1]+ps[1]) << 16);
                u.y = (unsigned)f2bf(pg[2]+ps[2]) | ((unsigned)f2bf(pg[3]+ps[3]) << 16);
                u.z = (unsigned)f2bf(pg[4]+ps[4]) | ((unsigned)f2bf(pg[5]+ps[5]) << 16);
                u.w = (unsigned)f2bf(pg[6]+ps[6]) | ((unsigned)f2bf(pg[7]+ps[7]) << 16);
            } else {                           // second K-segment: Wl
                const float* pl = Wl + o * 128 + (k - 128);
                u.x = (unsigned)f2bf(pl[0]) | ((unsigned)f2bf(pl[1]) << 16);
                u.y = (unsigned)f2bf(pl[2]) | ((unsigned)f2bf(pl[3]) << 16);
                u.z = (unsigned)f2bf(pl[4]) | ((unsigned)f2bf(pl[5]) << 16);
                u.w = (unsigned)f2bf(pl[6]) | ((unsigned)f2bf(pl[7]) << 16);
            }
            ((uint4*)Vp)[gid] = u;
        }
    } else if (bx < VP_BLOCKS + noffb) {
        int b = (bx - VP_BLOCKS) * 256 + t;
        if (b < nblk_g) {
            int target = b * GNPB;
            int lo = 0, hi = E;
            while (lo < hi) { int mid = (lo + hi) >> 1; if (dst[mid] < target) lo = mid + 1; else hi = mid; }
            blkoff[b] = lo;
        }
    } else {
        int gid = (bx - VP_BLOCKS - noffb) * 256 + t;
        if (gid < total8) {
            const float4* px = (const float4*)x + (size_t)gid * 2;
            float4 a = px[0], bq = px[1];
            uint4 u;
            u.x = (unsigned)f2bf(a.x)  | ((unsigned)f2bf(a.y)  << 16);
            u.y = (unsigned)f2bf(a.z)  | ((unsigned)f2bf(a.w)  << 16);
            u.z = (unsigned)f2bf(bq.x) | ((unsigned)f2bf(bq.y) << 16);
            u.w = (unsigned)f2bf(bq.z) | ((unsigned)f2bf(bq.w) << 16);
            ((uint4*)xb)[gid] = u;
        }
    }
}

// ---------------- Gather: M[n] = (deg>0) ? mean_e xb[src[e]] : 0  (bf16) ----------------
// One node per wave, 8 waves/block, barrier-free. lane = parity(p=lane>>4) x 16B-col(c).
// All row-loads (up to 8) issued before any accumulate -> 8 in flight per wave.
// (proven 141µs-version kernel, unchanged)
__global__ __launch_bounds__(512, 7)
void gather(const unsigned short* __restrict__ xb, const int* __restrict__ src,
            const int* __restrict__ deg, const int* __restrict__ blkoff,
            unsigned short* __restrict__ M, int N) {
    const int t = threadIdx.x, wv = t >> 6, lane = t & 63;
    const int c = lane & 15, p = lane >> 4;
    const int base = blockIdx.x * GNPB;

    // every wave redundantly scans the block's 8 degs (broadcast loads, no LDS/barrier)
    int dg8 = 0;
    if (lane < GNPB && base + lane < N) dg8 = deg[base + lane];
    int incl = dg8;
#pragma unroll
    for (int off = 1; off < GNPB; off <<= 1) {
        int v = __shfl_up(incl, off, 64);
        if (lane >= off) incl += v;
    }
    const int d = __shfl(dg8, wv, 64);
    const int s = blkoff[blockIdx.x] + __shfl(incl, wv, 64) - d;
    const int n = base + wv;
    if (n >= N) return;

    int idx = 0;
    if (lane < d) idx = src[s + lane];      // one coalesced shot, d <= 32

    const uint4* x4 = (const uint4*)xb;
    int r0 = __shfl(idx, p, 64),      r1 = __shfl(idx, p + 4, 64);
    int r2 = __shfl(idx, p + 8, 64),  r3 = __shfl(idx, p + 12, 64);
    uint4 v0 = x4[(size_t)r0 * 16 + c], v1 = x4[(size_t)r1 * 16 + c];
    uint4 v2 = x4[(size_t)r2 * 16 + c], v3 = x4[(size_t)r3 * 16 + c];
    uint4 v4, v5, v6, v7;
    const bool two = (d > 16);
    if (two) {                               // issue second batch BEFORE accumulating first
        int e = 16 + p;
        int r4 = __shfl(idx, e, 64),      r5 = __shfl(idx, e + 4, 64);
        int r6 = __shfl(idx, e + 8, 64),  r7 = __shfl(idx, e + 12, 64);
        v4 = x4[(size_t)r4 * 16 + c]; v5 = x4[(size_t)r5 * 16 + c];
        v6 = x4[(size_t)r6 * 16 + c]; v7 = x4[(size_t)r7 * 16 + c];
    }
    float a[8] = {0,0,0,0,0,0,0,0};
    float b[8] = {0,0,0,0,0,0,0,0};
    acc8(a, v0, (p      < d) ? ~0u : 0u);
    acc8(b, v1, (p + 4  < d) ? ~0u : 0u);
    acc8(a, v2, (p + 8  < d) ? ~0u : 0u);
    acc8(b, v3, (p + 12 < d) ? ~0u : 0u);
    if (two) {
        int e = 16 + p;
        acc8(a, v4, (e      < d) ? ~0u : 0u);
        acc8(b, v5, (e + 4  < d) ? ~0u : 0u);
        acc8(a, v6, (e + 8  < d) ? ~0u : 0u);
        acc8(b, v7, (e + 12 < d) ? ~0u : 0u);
    }
#pragma unroll
    for (int i = 0; i < 8; ++i) a[i] += b[i];
#pragma unroll
    for (int i = 0; i < 8; ++i) {
        a[i] += __shfl_xor(a[i], 16, 64);
        a[i] += __shfl_xor(a[i], 32, 64);
    }
    if (p == 0) {
        float inv = (d > 0) ? 1.0f / (float)d : 0.0f;
        uint4 u;
        u.x = (unsigned)f2bf(a[0]*inv) | ((unsigned)f2bf(a[1]*inv) << 16);
        u.y = (unsigned)f2bf(a[2]*inv) | ((unsigned)f2bf(a[3]*inv) << 16);
        u.z = (unsigned)f2bf(a[4]*inv) | ((unsigned)f2bf(a[5]*inv) << 16);
        u.w = (unsigned)f2bf(a[6]*inv) | ((unsigned)f2bf(a[7]*inv) << 16);
        ((uint4*)M)[(size_t)n * 16 + c] = u;
    }
}

// ---------------- GEMM: out = elu([xb | M] @ [Wg+Ws | Wl]^T + b), K=256 ----------------
// 16 rows/block, 3125 blocks, 256 threads. A-panel (xb row + M row, 512B -> padded 528B)
// staged ONCE -> single barrier. B streamed from packed Vp (contiguous 1KB wave reads,
// L2-resident) with register prefetch; no barriers in the K-loop. deg==0 rows are NOT
// stored (wrong under the fold) -> degfix owns them.
__global__ __launch_bounds__(256)
void gemm(const unsigned short* __restrict__ xb, const unsigned short* __restrict__ Mm,
          const int* __restrict__ deg, const unsigned short* __restrict__ Vp,
          const float* __restrict__ bias, float* __restrict__ out, int N) {
    __shared__ __align__(16) unsigned short As[MNPB * GAST];
    __shared__ unsigned char srowok[MNPB];
    const int t = threadIdx.x, wv = t >> 6, lane = t & 63;
    const int c = lane & 15, quad = lane >> 4;
    const int base = blockIdx.x * MNPB;

    if (t < MNPB) srowok[t] = (base + t < N && deg[base + t] > 0) ? 1 : 0;
#pragma unroll
    for (int it = 0; it < 2; ++it) {
        int f = it * 256 + t;
        int row = f >> 5, ch = f & 31;
        int grow = base + row; if (grow > N - 1) grow = N - 1;
        const unsigned short* gp = (ch < 16)
            ? xb + (size_t)grow * 128 + ch * 8
            : Mm + (size_t)grow * 128 + (ch - 16) * 8;
        uint4 val = *(const uint4*)gp;
        *(uint4*)(As + row * GAST + ch * 8) = val;
    }
    const int g0 = 2 * wv, g1 = 2 * wv + 1;
    const bf16x8* VB = (const bf16x8*)Vp;
    bf16x8 b0 = VB[(g0 * 8) * 64 + lane];       // B prefetch before the barrier
    bf16x8 b1 = VB[(g1 * 8) * 64 + lane];
    __syncthreads();

    f32x4 acc0 = (f32x4){0.f, 0.f, 0.f, 0.f};
    f32x4 acc1 = (f32x4){0.f, 0.f, 0.f, 0.f};
#pragma unroll
    for (int s2 = 0; s2 < 8; ++s2) {
        int sn = (s2 + 1 < 8) ? s2 + 1 : 0;     // branchless prefetch
        bf16x8 n0 = VB[(g0 * 8 + sn) * 64 + lane];
        bf16x8 n1 = VB[(g1 * 8 + sn) * 64 + lane];
        bf16x8 a0 = *(const bf16x8*)(As + c * GAST + s2 * 32 + quad * 8);
        acc0 = __builtin_amdgcn_mfma_f32_16x16x32_bf16(a0, b0, acc0, 0, 0, 0);
        acc1 = __builtin_amdgcn_mfma_f32_16x16x32_bf16(a0, b1, acc1, 0, 0, 0);
        b0 = n0; b1 = n1;
    }

    // epilogue: + bias, ELU (fast exp), store. C/D: col=lane&15, row=quad*4+reg
    const int col0 = g0 * 16 + c, col1 = g1 * 16 + c;
    const float bv0 = bias[col0], bv1 = bias[col1];
#pragma unroll
    for (int reg = 0; reg < 4; ++reg) {
        int lrow = quad * 4 + reg;
        int grow = base + lrow;
        if (grow < N && srowok[lrow]) {
            float v0 = acc0[reg] + bv0;
            float v1 = acc1[reg] + bv1;
            out[(size_t)grow * 128 + col0] = (v0 > 0.f) ? v0 : __expf(v0) - 1.0f;
            out[(size_t)grow * 128 + col1] = (v1 > 0.f) ? v1 : __expf(v1) - 1.0f;
        }
    }
}

// ---------------- degfix: write deg==0 rows with exact f32 elu(x@Wg.T + b) ----------------
// ~3% of nodes; independent of gather/gemm (gemm skips these rows). COALESCED layout:
// lane kl=lane&31 holds x[4kl..4kl+3]; wave halves cover even/odd output rows; Wg rows
// are read as coalesced float4 wave-loads (2 rows per instruction); 5-level shfl_xor
// butterfly (within 32-lane halves) reduces 4 partials at a time. Replaces the
// lane-private row walk that cost 42.5 µs at 4x L2 sector over-fetch.
__global__ __launch_bounds__(256)
void degfix(const float* __restrict__ x, const float* __restrict__ Wg,
            const float* __restrict__ bias, const int* __restrict__ deg,
            float* __restrict__ out, int N) {
    const int t = threadIdx.x, lane = t & 63;
    const int nb = blockIdx.x * 256 + t;
    int d = 1;
    if (nb < N) d = deg[nb];
    unsigned long long m = __ballot(d == 0);
    const int wbase = blockIdx.x * 256 + ((t >> 6) << 6);
    const int half = lane >> 5;          // 0: even rows, 1: odd rows
    const int kl   = lane & 31;          // covers k = 4*kl .. 4*kl+3
    while (m) {
        int bit = __builtin_ctzll(m);
        m &= m - 1;
        int n = wbase + bit;
        const float4 xv = ((const float4*)(x + (size_t)n * 128))[kl];
        float* orow = out + (size_t)n * 128;
#pragma unroll 1
        for (int o = 0; o < 128; o += 8) {
            float4 w0 = ((const float4*)(Wg + (size_t)(o + 0 + half) * 128))[kl];
            float4 w1 = ((const float4*)(Wg + (size_t)(o + 2 + half) * 128))[kl];
            float4 w2 = ((const float4*)(Wg + (size_t)(o + 4 + half) * 128))[kl];
            float4 w3 = ((const float4*)(Wg + (size_t)(o + 6 + half) * 128))[kl];
            float s0 = xv.x*w0.x + xv.y*w0.y + xv.z*w0.z + xv.w*w0.w;
            float s1 = xv.x*w1.x + xv.y*w1.y + xv.z*w1.z + xv.w*w1.w;
            float s2 = xv.x*w2.x + xv.y*w2.y + xv.z*w2.z + xv.w*w2.w;
            float s3 = xv.x*w3.x + xv.y*w3.y + xv.z*w3.z + xv.w*w3.w;
#pragma unroll
            for (int off = 1; off < 32; off <<= 1) {   // stays within each 32-lane half
                s0 += __shfl_xor(s0, off, 64);
                s1 += __shfl_xor(s1, off, 64);
                s2 += __shfl_xor(s2, off, 64);
                s3 += __shfl_xor(s3, off, 64);
            }
            if (kl == 0) {                              // lanes 0 and 32 write 4 cols each
                int c0 = o + 0 + half; float v0 = s0 + bias[c0];
                orow[c0] = (v0 > 0.f) ? v0 : __expf(v0) - 1.0f;
                int c1 = o + 2 + half; float v1 = s1 + bias[c1];
                orow[c1] = (v1 > 0.f) ? v1 : __expf(v1) - 1.0f;
                int c2 = o + 4 + half; float v2 = s2 + bias[c2];
                orow[c2] = (v2 > 0.f) ? v2 : __expf(v2) - 1.0f;
                int c3 = o + 6 + half; float v3 = s3 + bias[c3];
                orow[c3] = (v3 > 0.f) ? v3 : __expf(v3) - 1.0f;
            }
        }
    }
}

extern "C" void kernel_launch(void* const* d_in, const int* in_sizes, int n_in,
                              void* d_out, int out_size, void* d_ws, size_t ws_size,
                              hipStream_t stream) {
    const float* x  = (const float*)d_in[0];
    const float* Wg = (const float*)d_in[1];
    const float* Wl = (const float*)d_in[2];
    const float* Ws = (const float*)d_in[3];
    const float* b  = (const float*)d_in[4];
    const int*   src = (const int*)d_in[5];
    const int*   dst = (const int*)d_in[6];
    const int*   deg = (const int*)d_in[7];
    const int E = in_sizes[5];
    const int N = in_sizes[7];
    float* out = (float*)d_out;

    const size_t NB = (size_t)N * 128 * 2;                       // 12.8 MB
    unsigned short* Vp     = (unsigned short*)d_ws;              // 64 KB (packed B, K=256)
    int*            blkoff = (int*)((char*)d_ws + 65536);        // 32 KB reserved
    unsigned short* xb     = (unsigned short*)((char*)d_ws + 98304);
    unsigned short* Mm     = (unsigned short*)((char*)d_ws + 98304 + NB);

    const int nblk_g = (N + GNPB - 1) / GNPB;      // 6250
    const int noffb  = (nblk_g + 255) / 256;       // 25
    const int total8 = N * 16;
    const int nconv  = (total8 + 255) / 256;       // 3125

    prep<<<dim3(VP_BLOCKS + noffb + nconv), dim3(256), 0, stream>>>(
        x, Wg, Wl, Ws, dst, Vp, xb, blkoff, total8, nblk_g, noffb, E);
    gather<<<dim3(nblk_g), dim3(512), 0, stream>>>(xb, src, deg, blkoff, Mm, N);
    gemm<<<dim3((N + MNPB - 1) / MNPB), dim3(256), 0, stream>>>(xb, Mm, deg, Vp, b, out, N);
    degfix<<<dim3((N + 255) / 256), dim3(256), 0, stream>>>(x, Wg, b, deg, out, N);
}

// Round 4
// 161.866 us; speedup vs baseline: 1.2610x; 1.2610x over previous
//
#include <hip/hip_runtime.h>
#include <cstdint>
#include <cstddef>

#define GNPB 8        // nodes per gather block (8 waves, 1 node/wave)
#define MNPB 16       // rows per gemm block
#define GAST 264      // gemm LDS A row stride in elems (528 B) — breaks 512B-stride banks
#define VP_BLOCKS 16  // prep blocks packing Vp (4096 threads, K=256)

typedef __attribute__((ext_vector_type(8))) short bf16x8;
typedef __attribute__((ext_vector_type(4))) float f32x4;

static __device__ __forceinline__ unsigned short f2bf(float f) {
    unsigned int u = __builtin_bit_cast(unsigned int, f);
    u += 0x7fffu + ((u >> 16) & 1u);
    return (unsigned short)(u >> 16);
}
static __device__ __forceinline__ float bfhi(unsigned int u) { return __builtin_bit_cast(float, u & 0xFFFF0000u); }
static __device__ __forceinline__ float bflo(unsigned int u) { return __builtin_bit_cast(float, u << 16); }
// masked bf16x8 accumulate: m = all-ones keeps, 0 zeroes (bf16 0x0000 == +0.0)
static __device__ __forceinline__ void acc8(float* a, const uint4& v, unsigned m) {
    unsigned x0 = v.x & m, x1 = v.y & m, x2 = v.z & m, x3 = v.w & m;
    a[0] += bflo(x0); a[1] += bfhi(x0); a[2] += bflo(x1); a[3] += bfhi(x1);
    a[4] += bflo(x2); a[5] += bfhi(x2); a[6] += bflo(x3); a[7] += bfhi(x3);
}

// ---------------- Prep: Vp pack (B = [Wg+Ws | Wl], K=256), xb = bf16(x), blkoff ----------------
// Vp layout: element ((g*8 + s)*64 + lane)*8 + j = B1[g*16 + (lane&15)][s*32 + (lane>>4)*8 + j]
// so a wave's B-fragment load for (col-group g, kstep s) is ONE contiguous 1KB read.
__global__ __launch_bounds__(256)
void prep(const float* __restrict__ x, const float* __restrict__ Wg,
          const float* __restrict__ Wl, const float* __restrict__ Ws,
          const int* __restrict__ dst, unsigned short* __restrict__ Vp,
          unsigned short* __restrict__ xb, int* __restrict__ blkoff,
          int total8, int nblk_g, int noffb, int E) {
    const int bx = blockIdx.x, t = threadIdx.x;
    if (bx < VP_BLOCKS) {
        int gid = bx * 256 + t;
        if (gid < 4096) {
            int l = gid & 63, srow = (gid >> 6) & 7, g = gid >> 9;
            int o = g * 16 + (l & 15);
            int k = srow * 32 + (l >> 4) * 8;
            uint4 u;
            if (k < 128) {                     // first K-segment: W1 = Wg + Ws (fold verified R1)
                const float* pg = Wg + o * 128 + k;
                const float* ps = Ws + o * 128 + k;
                u.x = (unsigned)f2bf(pg[0]+ps[0]) | ((unsigned)f2bf(pg[1]+ps[1]) << 16);
                u.y = (unsigned)f2bf(pg[2]+ps[2]) | ((unsigned)f2bf(pg[3]+ps[3]) << 16);
                u.z = (unsigned)f2bf(pg[4]+ps[4]) | ((unsigned)f2bf(pg[5]+ps[5]) << 16);
                u.w = (unsigned)f2bf(pg[6]+ps[6]) | ((unsigned)f2bf(pg[7]+ps[7]) << 16);
            } else {                           // second K-segment: Wl
                const float* pl = Wl + o * 128 + (k - 128);
                u.x = (unsigned)f2bf(pl[0]) | ((unsigned)f2bf(pl[1]) << 16);
                u.y = (unsigned)f2bf(pl[2]) | ((unsigned)f2bf(pl[3]) << 16);
                u.z = (unsigned)f2bf(pl[4]) | ((unsigned)f2bf(pl[5]) << 16);
                u.w = (unsigned)f2bf(pl[6]) | ((unsigned)f2bf(pl[7]) << 16);
            }
            ((uint4*)Vp)[gid] = u;
        }
    } else if (bx < VP_BLOCKS + noffb) {
        int b = (bx - VP_BLOCKS) * 256 + t;
        if (b < nblk_g) {
            int target = b * GNPB;
            int lo = 0, hi = E;
            while (lo < hi) { int mid = (lo + hi) >> 1; if (dst[mid] < target) lo = mid + 1; else hi = mid; }
            blkoff[b] = lo;
        }
    } else {
        int gid = (bx - VP_BLOCKS - noffb) * 256 + t;
        if (gid < total8) {
            const float4* px = (const float4*)x + (size_t)gid * 2;
            float4 a = px[0], bq = px[1];
            uint4 u;
            u.x = (unsigned)f2bf(a.x)  | ((unsigned)f2bf(a.y)  << 16);
            u.y = (unsigned)f2bf(a.z)  | ((unsigned)f2bf(a.w)  << 16);
            u.z = (unsigned)f2bf(bq.x) | ((unsigned)f2bf(bq.y) << 16);
            u.w = (unsigned)f2bf(bq.z) | ((unsigned)f2bf(bq.w) << 16);
            ((uint4*)xb)[gid] = u;
        }
    }
}

// ---------------- Gather: M[n] = (deg>0) ? mean_e xb[src[e]] : 0  (bf16) ----------------
// One node per wave, 8 waves/block, barrier-free. lane = parity(p=lane>>4) x 16B-col(c).
// All row-loads (up to 8) issued before any accumulate -> 8 in flight per wave.
// (proven 141µs-version kernel, unchanged)
__global__ __launch_bounds__(512, 7)
void gather(const unsigned short* __restrict__ xb, const int* __restrict__ src,
            const int* __restrict__ deg, const int* __restrict__ blkoff,
            unsigned short* __restrict__ M, int N) {
    const int t = threadIdx.x, wv = t >> 6, lane = t & 63;
    const int c = lane & 15, p = lane >> 4;
    const int base = blockIdx.x * GNPB;

    // every wave redundantly scans the block's 8 degs (broadcast loads, no LDS/barrier)
    int dg8 = 0;
    if (lane < GNPB && base + lane < N) dg8 = deg[base + lane];
    int incl = dg8;
#pragma unroll
    for (int off = 1; off < GNPB; off <<= 1) {
        int v = __shfl_up(incl, off, 64);
        if (lane >= off) incl += v;
    }
    const int d = __shfl(dg8, wv, 64);
    const int s = blkoff[blockIdx.x] + __shfl(incl, wv, 64) - d;
    const int n = base + wv;
    if (n >= N) return;

    int idx = 0;
    if (lane < d) idx = src[s + lane];      // one coalesced shot, d <= 32

    const uint4* x4 = (const uint4*)xb;
    int r0 = __shfl(idx, p, 64),      r1 = __shfl(idx, p + 4, 64);
    int r2 = __shfl(idx, p + 8, 64),  r3 = __shfl(idx, p + 12, 64);
    uint4 v0 = x4[(size_t)r0 * 16 + c], v1 = x4[(size_t)r1 * 16 + c];
    uint4 v2 = x4[(size_t)r2 * 16 + c], v3 = x4[(size_t)r3 * 16 + c];
    uint4 v4, v5, v6, v7;
    const bool two = (d > 16);
    if (two) {                               // issue second batch BEFORE accumulating first
        int e = 16 + p;
        int r4 = __shfl(idx, e, 64),      r5 = __shfl(idx, e + 4, 64);
        int r6 = __shfl(idx, e + 8, 64),  r7 = __shfl(idx, e + 12, 64);
        v4 = x4[(size_t)r4 * 16 + c]; v5 = x4[(size_t)r5 * 16 + c];
        v6 = x4[(size_t)r6 * 16 + c]; v7 = x4[(size_t)r7 * 16 + c];
    }
    float a[8] = {0,0,0,0,0,0,0,0};
    float b[8] = {0,0,0,0,0,0,0,0};
    acc8(a, v0, (p      < d) ? ~0u : 0u);
    acc8(b, v1, (p + 4  < d) ? ~0u : 0u);
    acc8(a, v2, (p + 8  < d) ? ~0u : 0u);
    acc8(b, v3, (p + 12 < d) ? ~0u : 0u);
    if (two) {
        int e = 16 + p;
        acc8(a, v4, (e      < d) ? ~0u : 0u);
        acc8(b, v5, (e + 4  < d) ? ~0u : 0u);
        acc8(a, v6, (e + 8  < d) ? ~0u : 0u);
        acc8(b, v7, (e + 12 < d) ? ~0u : 0u);
    }
#pragma unroll
    for (int i = 0; i < 8; ++i) a[i] += b[i];
#pragma unroll
    for (int i = 0; i < 8; ++i) {
        a[i] += __shfl_xor(a[i], 16, 64);
        a[i] += __shfl_xor(a[i], 32, 64);
    }
    if (p == 0) {
        float inv = (d > 0) ? 1.0f / (float)d : 0.0f;
        uint4 u;
        u.x = (unsigned)f2bf(a[0]*inv) | ((unsigned)f2bf(a[1]*inv) << 16);
        u.y = (unsigned)f2bf(a[2]*inv) | ((unsigned)f2bf(a[3]*inv) << 16);
        u.z = (unsigned)f2bf(a[4]*inv) | ((unsigned)f2bf(a[5]*inv) << 16);
        u.w = (unsigned)f2bf(a[6]*inv) | ((unsigned)f2bf(a[7]*inv) << 16);
        ((uint4*)M)[(size_t)n * 16 + c] = u;
    }
}

// ---------------- GEMM: out = elu([xb | M] @ [Wg+Ws | Wl]^T + b), K=256 ----------------
// 16 rows/block, 3125 blocks, 256 threads. A-panel (xb row + M row, 512B -> padded 528B)
// staged ONCE -> single barrier. B streamed from packed Vp (contiguous 1KB wave reads,
// L2-resident) with register prefetch; no barriers in the K-loop. deg==0 rows are NOT
// stored (wrong under the fold) -> degfix owns them.
__global__ __launch_bounds__(256)
void gemm(const unsigned short* __restrict__ xb, const unsigned short* __restrict__ Mm,
          const int* __restrict__ deg, const unsigned short* __restrict__ Vp,
          const float* __restrict__ bias, float* __restrict__ out, int N) {
    __shared__ __align__(16) unsigned short As[MNPB * GAST];
    __shared__ unsigned char srowok[MNPB];
    const int t = threadIdx.x, wv = t >> 6, lane = t & 63;
    const int c = lane & 15, quad = lane >> 4;
    const int base = blockIdx.x * MNPB;

    if (t < MNPB) srowok[t] = (base + t < N && deg[base + t] > 0) ? 1 : 0;
#pragma unroll
    for (int it = 0; it < 2; ++it) {
        int f = it * 256 + t;
        int row = f >> 5, ch = f & 31;
        int grow = base + row; if (grow > N - 1) grow = N - 1;
        const unsigned short* gp = (ch < 16)
            ? xb + (size_t)grow * 128 + ch * 8
            : Mm + (size_t)grow * 128 + (ch - 16) * 8;
        uint4 val = *(const uint4*)gp;
        *(uint4*)(As + row * GAST + ch * 8) = val;
    }
    const int g0 = 2 * wv, g1 = 2 * wv + 1;
    const bf16x8* VB = (const bf16x8*)Vp;
    bf16x8 b0 = VB[(g0 * 8) * 64 + lane];       // B prefetch before the barrier
    bf16x8 b1 = VB[(g1 * 8) * 64 + lane];
    __syncthreads();

    f32x4 acc0 = (f32x4){0.f, 0.f, 0.f, 0.f};
    f32x4 acc1 = (f32x4){0.f, 0.f, 0.f, 0.f};
#pragma unroll
    for (int s2 = 0; s2 < 8; ++s2) {
        int sn = (s2 + 1 < 8) ? s2 + 1 : 0;     // branchless prefetch
        bf16x8 n0 = VB[(g0 * 8 + sn) * 64 + lane];
        bf16x8 n1 = VB[(g1 * 8 + sn) * 64 + lane];
        bf16x8 a0 = *(const bf16x8*)(As + c * GAST + s2 * 32 + quad * 8);
        acc0 = __builtin_amdgcn_mfma_f32_16x16x32_bf16(a0, b0, acc0, 0, 0, 0);
        acc1 = __builtin_amdgcn_mfma_f32_16x16x32_bf16(a0, b1, acc1, 0, 0, 0);
        b0 = n0; b1 = n1;
    }

    // epilogue: + bias, ELU (fast exp), store. C/D: col=lane&15, row=quad*4+reg
    const int col0 = g0 * 16 + c, col1 = g1 * 16 + c;
    const float bv0 = bias[col0], bv1 = bias[col1];
#pragma unroll
    for (int reg = 0; reg < 4; ++reg) {
        int lrow = quad * 4 + reg;
        int grow = base + lrow;
        if (grow < N && srowok[lrow]) {
            float v0 = acc0[reg] + bv0;
            float v1 = acc1[reg] + bv1;
            out[(size_t)grow * 128 + col0] = (v0 > 0.f) ? v0 : __expf(v0) - 1.0f;
            out[(size_t)grow * 128 + col1] = (v1 > 0.f) ? v1 : __expf(v1) - 1.0f;
        }
    }
}

// ---------------- degfix: write deg==0 rows with exact f32 elu(x@Wg.T + b) ----------------
// One block per 64 candidate nodes. Block compacts its deg==0 nodes into LDS (avg ~2,
// 14% of blocks early-exit with none), then loads each thread's Wg slice ONCE into 16
// float4 registers (thread t -> col t>>1, K-half t&1; block collectively holds all of
// Wg). Per node: 16 broadcast x-row loads + 64 FMA + ONE shfl_xor. Kills both failure
// modes of R2/R3: no per-node Wg re-reads, no deep shuffle chains, no straggler wave.
__global__ __launch_bounds__(256)
void degfix(const float* __restrict__ x, const float* __restrict__ Wg,
            const float* __restrict__ bias, const int* __restrict__ deg,
            float* __restrict__ out, int N) {
    __shared__ int nds[64];
    __shared__ int ncnt;
    const int t = threadIdx.x;
    const int base = blockIdx.x * 64;
    if (t == 0) ncnt = 0;
    __syncthreads();
    if (t < 64) {
        int n = base + t;
        if (n < N && deg[n] == 0) {
            int i = atomicAdd(&ncnt, 1);
            nds[i] = n;
        }
    }
    __syncthreads();
    const int cnt = ncnt;
    if (cnt == 0) return;

    const int c = t >> 1, h = t & 1;          // col, K-half
    const float4* wp = (const float4*)(Wg + (size_t)c * 128 + h * 64);
    float4 w[16];
#pragma unroll
    for (int j = 0; j < 16; ++j) w[j] = wp[j];   // Wg resident in regs for all nodes
    const float bv = bias[c];

    for (int i = 0; i < cnt; ++i) {
        const int n = nds[i];
        const float4* xr = (const float4*)(x + (size_t)n * 128) + h * 16;
        float s0 = 0.f, s1 = 0.f, s2 = 0.f, s3 = 0.f;
#pragma unroll
        for (int j = 0; j < 16; j += 4) {      // 4 independent FMA chains
            float4 xv0 = xr[j], xv1 = xr[j+1], xv2 = xr[j+2], xv3 = xr[j+3];
            s0 += xv0.x*w[j].x   + xv0.y*w[j].y   + xv0.z*w[j].z   + xv0.w*w[j].w;
            s1 += xv1.x*w[j+1].x + xv1.y*w[j+1].y + xv1.z*w[j+1].z + xv1.w*w[j+1].w;
            s2 += xv2.x*w[j+2].x + xv2.y*w[j+2].y + xv2.z*w[j+2].z + xv2.w*w[j+2].w;
            s3 += xv3.x*w[j+3].x + xv3.y*w[j+3].y + xv3.z*w[j+3].z + xv3.w*w[j+3].w;
        }
        float s = (s0 + s1) + (s2 + s3);
        s += __shfl_xor(s, 1, 64);             // combine the two K-halves
        if (h == 0) {
            float v = s + bv;
            out[(size_t)n * 128 + c] = (v > 0.f) ? v : __expf(v) - 1.0f;
        }
    }
}

extern "C" void kernel_launch(void* const* d_in, const int* in_sizes, int n_in,
                              void* d_out, int out_size, void* d_ws, size_t ws_size,
                              hipStream_t stream) {
    const float* x  = (const float*)d_in[0];
    const float* Wg = (const float*)d_in[1];
    const float* Wl = (const float*)d_in[2];
    const float* Ws = (const float*)d_in[3];
    const float* b  = (const float*)d_in[4];
    const int*   src = (const int*)d_in[5];
    const int*   dst = (const int*)d_in[6];
    const int*   deg = (const int*)d_in[7];
    const int E = in_sizes[5];
    const int N = in_sizes[7];
    float* out = (float*)d_out;

    const size_t NB = (size_t)N * 128 * 2;                       // 12.8 MB
    unsigned short* Vp     = (unsigned short*)d_ws;              // 64 KB (packed B, K=256)
    int*            blkoff = (int*)((char*)d_ws + 65536);        // 32 KB reserved
    unsigned short* xb     = (unsigned short*)((char*)d_ws + 98304);
    unsigned short* Mm     = (unsigned short*)((char*)d_ws + 98304 + NB);

    const int nblk_g = (N + GNPB - 1) / GNPB;      // 6250
    const int noffb  = (nblk_g + 255) / 256;       // 25
    const int total8 = N * 16;
    const int nconv  = (total8 + 255) / 256;       // 3125

    prep<<<dim3(VP_BLOCKS + noffb + nconv), dim3(256), 0, stream>>>(
        x, Wg, Wl, Ws, dst, Vp, xb, blkoff, total8, nblk_g, noffb, E);
    gather<<<dim3(nblk_g), dim3(512), 0, stream>>>(xb, src, deg, blkoff, Mm, N);
    gemm<<<dim3((N + MNPB - 1) / MNPB), dim3(256), 0, stream>>>(xb, Mm, deg, Vp, b, out, N);
    degfix<<<dim3((N + 63) / 64), dim3(256), 0, stream>>>(x, Wg, b, deg, out, N);
}

// Round 5
// 148.872 us; speedup vs baseline: 1.3711x; 1.0873x over previous
//
#include <hip/hip_runtime.h>
#include <cstdint>
#include <cstddef>

#define GNPB 8        // nodes per gather block (8 waves, 1 node/wave)
#define MNPB 64       // rows per gemm block (4 row-tiles of 16)
#define GAST 264      // gemm LDS A row stride in elems (528 B) — breaks 512B-stride banks
#define DAST 136      // degfix LDS A row stride (K=128 + 8 pad)
#define VP_BLOCKS 16  // prep blocks packing Vp (4096 threads, K=256)
#define VPG_BLOCKS 8  // prep blocks packing Vpg (2048 threads, K=128, Wg only)

typedef __attribute__((ext_vector_type(8))) short bf16x8;
typedef __attribute__((ext_vector_type(4))) float f32x4;

static __device__ __forceinline__ unsigned short f2bf(float f) {
    unsigned int u = __builtin_bit_cast(unsigned int, f);
    u += 0x7fffu + ((u >> 16) & 1u);
    return (unsigned short)(u >> 16);
}
static __device__ __forceinline__ float bfhi(unsigned int u) { return __builtin_bit_cast(float, u & 0xFFFF0000u); }
static __device__ __forceinline__ float bflo(unsigned int u) { return __builtin_bit_cast(float, u << 16); }
// masked bf16x8 accumulate: m = all-ones keeps, 0 zeroes (bf16 0x0000 == +0.0)
static __device__ __forceinline__ void acc8(float* a, const uint4& v, unsigned m) {
    unsigned x0 = v.x & m, x1 = v.y & m, x2 = v.z & m, x3 = v.w & m;
    a[0] += bflo(x0); a[1] += bfhi(x0); a[2] += bflo(x1); a[3] += bfhi(x1);
    a[4] += bflo(x2); a[5] += bfhi(x2); a[6] += bflo(x3); a[7] += bfhi(x3);
}

// ---------------- Prep: Vp/Vpg pack, xb = bf16(x), blkoff, deg0 compaction ----------------
// Vp layout: element ((g*8 + s)*64 + lane)*8 + j = B1[g*16 + (lane&15)][s*32 + (lane>>4)*8 + j]
// (B1 = [Wg+Ws | Wl], K=256). Vpg: same pattern, 4 k-steps, Wg only (K=128).
__global__ __launch_bounds__(256)
void prep(const float* __restrict__ x, const float* __restrict__ Wg,
          const float* __restrict__ Wl, const float* __restrict__ Ws,
          const int* __restrict__ dst, const int* __restrict__ deg,
          unsigned short* __restrict__ Vp, unsigned short* __restrict__ Vpg,
          unsigned short* __restrict__ xb, int* __restrict__ blkoff,
          int* __restrict__ d0cnt, int* __restrict__ d0list,
          int total8, int nblk_g, int noffb, int ncmp, int E, int N) {
    const int bx = blockIdx.x, t = threadIdx.x;
    if (bx < VP_BLOCKS) {
        int gid = bx * 256 + t;
        if (gid < 4096) {
            int l = gid & 63, srow = (gid >> 6) & 7, g = gid >> 9;
            int o = g * 16 + (l & 15);
            int k = srow * 32 + (l >> 4) * 8;
            uint4 u;
            if (k < 128) {                     // first K-segment: W1 = Wg + Ws
                const float* pg = Wg + o * 128 + k;
                const float* ps = Ws + o * 128 + k;
                u.x = (unsigned)f2bf(pg[0]+ps[0]) | ((unsigned)f2bf(pg[1]+ps[1]) << 16);
                u.y = (unsigned)f2bf(pg[2]+ps[2]) | ((unsigned)f2bf(pg[3]+ps[3]) << 16);
                u.z = (unsigned)f2bf(pg[4]+ps[4]) | ((unsigned)f2bf(pg[5]+ps[5]) << 16);
                u.w = (unsigned)f2bf(pg[6]+ps[6]) | ((unsigned)f2bf(pg[7]+ps[7]) << 16);
            } else {                           // second K-segment: Wl
                const float* pl = Wl + o * 128 + (k - 128);
                u.x = (unsigned)f2bf(pl[0]) | ((unsigned)f2bf(pl[1]) << 16);
                u.y = (unsigned)f2bf(pl[2]) | ((unsigned)f2bf(pl[3]) << 16);
                u.z = (unsigned)f2bf(pl[4]) | ((unsigned)f2bf(pl[5]) << 16);
                u.w = (unsigned)f2bf(pl[6]) | ((unsigned)f2bf(pl[7]) << 16);
            }
            ((uint4*)Vp)[gid] = u;
        }
    } else if (bx < VP_BLOCKS + VPG_BLOCKS) {
        int gid = (bx - VP_BLOCKS) * 256 + t;  // 2048 entries: Wg-only panel, K=128
        if (gid < 2048) {
            int l = gid & 63, s = (gid >> 6) & 3, g = gid >> 8;
            int o = g * 16 + (l & 15);
            int k = s * 32 + (l >> 4) * 8;
            const float* p = Wg + o * 128 + k;
            uint4 u;
            u.x = (unsigned)f2bf(p[0]) | ((unsigned)f2bf(p[1]) << 16);
            u.y = (unsigned)f2bf(p[2]) | ((unsigned)f2bf(p[3]) << 16);
            u.z = (unsigned)f2bf(p[4]) | ((unsigned)f2bf(p[5]) << 16);
            u.w = (unsigned)f2bf(p[6]) | ((unsigned)f2bf(p[7]) << 16);
            ((uint4*)Vpg)[gid] = u;
        }
    } else if (bx < VP_BLOCKS + VPG_BLOCKS + noffb) {
        int b = (bx - VP_BLOCKS - VPG_BLOCKS) * 256 + t;
        if (b < nblk_g) {
            int target = b * GNPB;
            int lo = 0, hi = E;
            while (lo < hi) { int mid = (lo + hi) >> 1; if (dst[mid] < target) lo = mid + 1; else hi = mid; }
            blkoff[b] = lo;
        }
    } else if (bx < VP_BLOCKS + VPG_BLOCKS + noffb + ncmp) {
        int n = (bx - VP_BLOCKS - VPG_BLOCKS - noffb) * 256 + t;
        if (n < N && deg[n] == 0) {
            int i = atomicAdd(d0cnt, 1);       // device-scope; order irrelevant
            d0list[i] = n;
        }
    } else {
        int gid = (bx - VP_BLOCKS - VPG_BLOCKS - noffb - ncmp) * 256 + t;
        if (gid < total8) {
            const float4* px = (const float4*)x + (size_t)gid * 2;
            float4 a = px[0], bq = px[1];
            uint4 u;
            u.x = (unsigned)f2bf(a.x)  | ((unsigned)f2bf(a.y)  << 16);
            u.y = (unsigned)f2bf(a.z)  | ((unsigned)f2bf(a.w)  << 16);
            u.z = (unsigned)f2bf(bq.x) | ((unsigned)f2bf(bq.y) << 16);
            u.w = (unsigned)f2bf(bq.z) | ((unsigned)f2bf(bq.w) << 16);
            ((uint4*)xb)[gid] = u;
        }
    }
}

// ---------------- Gather: M[n] = (deg>0) ? mean_e xb[src[e]] : 0  (bf16) ----------------
// One node per wave, 8 waves/block, barrier-free. (proven kernel, unchanged)
__global__ __launch_bounds__(512, 7)
void gather(const unsigned short* __restrict__ xb, const int* __restrict__ src,
            const int* __restrict__ deg, const int* __restrict__ blkoff,
            unsigned short* __restrict__ M, int N) {
    const int t = threadIdx.x, wv = t >> 6, lane = t & 63;
    const int c = lane & 15, p = lane >> 4;
    const int base = blockIdx.x * GNPB;

    int dg8 = 0;
    if (lane < GNPB && base + lane < N) dg8 = deg[base + lane];
    int incl = dg8;
#pragma unroll
    for (int off = 1; off < GNPB; off <<= 1) {
        int v = __shfl_up(incl, off, 64);
        if (lane >= off) incl += v;
    }
    const int d = __shfl(dg8, wv, 64);
    const int s = blkoff[blockIdx.x] + __shfl(incl, wv, 64) - d;
    const int n = base + wv;
    if (n >= N) return;

    int idx = 0;
    if (lane < d) idx = src[s + lane];      // one coalesced shot, d <= 32

    const uint4* x4 = (const uint4*)xb;
    int r0 = __shfl(idx, p, 64),      r1 = __shfl(idx, p + 4, 64);
    int r2 = __shfl(idx, p + 8, 64),  r3 = __shfl(idx, p + 12, 64);
    uint4 v0 = x4[(size_t)r0 * 16 + c], v1 = x4[(size_t)r1 * 16 + c];
    uint4 v2 = x4[(size_t)r2 * 16 + c], v3 = x4[(size_t)r3 * 16 + c];
    uint4 v4, v5, v6, v7;
    const bool two = (d > 16);
    if (two) {                               // issue second batch BEFORE accumulating first
        int e = 16 + p;
        int r4 = __shfl(idx, e, 64),      r5 = __shfl(idx, e + 4, 64);
        int r6 = __shfl(idx, e + 8, 64),  r7 = __shfl(idx, e + 12, 64);
        v4 = x4[(size_t)r4 * 16 + c]; v5 = x4[(size_t)r5 * 16 + c];
        v6 = x4[(size_t)r6 * 16 + c]; v7 = x4[(size_t)r7 * 16 + c];
    }
    float a[8] = {0,0,0,0,0,0,0,0};
    float b[8] = {0,0,0,0,0,0,0,0};
    acc8(a, v0, (p      < d) ? ~0u : 0u);
    acc8(b, v1, (p + 4  < d) ? ~0u : 0u);
    acc8(a, v2, (p + 8  < d) ? ~0u : 0u);
    acc8(b, v3, (p + 12 < d) ? ~0u : 0u);
    if (two) {
        int e = 16 + p;
        acc8(a, v4, (e      < d) ? ~0u : 0u);
        acc8(b, v5, (e + 4  < d) ? ~0u : 0u);
        acc8(a, v6, (e + 8  < d) ? ~0u : 0u);
        acc8(b, v7, (e + 12 < d) ? ~0u : 0u);
    }
#pragma unroll
    for (int i = 0; i < 8; ++i) a[i] += b[i];
#pragma unroll
    for (int i = 0; i < 8; ++i) {
        a[i] += __shfl_xor(a[i], 16, 64);
        a[i] += __shfl_xor(a[i], 32, 64);
    }
    if (p == 0) {
        float inv = (d > 0) ? 1.0f / (float)d : 0.0f;
        uint4 u;
        u.x = (unsigned)f2bf(a[0]*inv) | ((unsigned)f2bf(a[1]*inv) << 16);
        u.y = (unsigned)f2bf(a[2]*inv) | ((unsigned)f2bf(a[3]*inv) << 16);
        u.z = (unsigned)f2bf(a[4]*inv) | ((unsigned)f2bf(a[5]*inv) << 16);
        u.w = (unsigned)f2bf(a[6]*inv) | ((unsigned)f2bf(a[7]*inv) << 16);
        ((uint4*)M)[(size_t)n * 16 + c] = u;
    }
}

// ---------------- GEMM: out = elu([xb | M] @ [Wg+Ws | Wl]^T + b), K=256 ----------------
// 64 rows/block (4 row-tiles), 782 blocks, 256 threads. Each wave: 2 col-groups × 4
// row-tiles = 8 accumulators; every B-fragment is reused across 4 row-tiles -> Vp L2
// traffic 200->50 MB. Stores ALL rows; degfix overwrites deg==0 rows afterwards.
__global__ __launch_bounds__(256)
void gemm(const unsigned short* __restrict__ xb, const unsigned short* __restrict__ Mm,
          const unsigned short* __restrict__ Vp, const float* __restrict__ bias,
          float* __restrict__ out, int N) {
    __shared__ __align__(16) unsigned short As[MNPB * GAST];   // 33792 B
    const int t = threadIdx.x, wv = t >> 6, lane = t & 63;
    const int c = lane & 15, quad = lane >> 4;
    const int base = blockIdx.x * MNPB;

#pragma unroll
    for (int it = 0; it < 8; ++it) {           // 64 rows × 32 16B-chunks
        int f = it * 256 + t;
        int row = f >> 5, ch = f & 31;
        int grow = base + row; if (grow > N - 1) grow = N - 1;
        const unsigned short* gp = (ch < 16)
            ? xb + (size_t)grow * 128 + ch * 8
            : Mm + (size_t)grow * 128 + (ch - 16) * 8;
        uint4 val = *(const uint4*)gp;
        *(uint4*)(As + row * GAST + ch * 8) = val;
    }
    const int g0 = 2 * wv, g1 = 2 * wv + 1;
    const bf16x8* VB = (const bf16x8*)Vp;
    bf16x8 b0 = VB[(g0 * 8) * 64 + lane];       // B prefetch before the barrier
    bf16x8 b1 = VB[(g1 * 8) * 64 + lane];
    __syncthreads();

    f32x4 acc0[4], acc1[4];
#pragma unroll
    for (int rt = 0; rt < 4; ++rt) { acc0[rt] = (f32x4){0.f,0.f,0.f,0.f}; acc1[rt] = (f32x4){0.f,0.f,0.f,0.f}; }
#pragma unroll
    for (int s2 = 0; s2 < 8; ++s2) {
        int sn = (s2 + 1) & 7;                  // branchless prefetch
        bf16x8 n0 = VB[(g0 * 8 + sn) * 64 + lane];
        bf16x8 n1 = VB[(g1 * 8 + sn) * 64 + lane];
#pragma unroll
        for (int rt = 0; rt < 4; ++rt) {        // B reused across 4 row-tiles
            bf16x8 a0 = *(const bf16x8*)(As + (rt * 16 + c) * GAST + s2 * 32 + quad * 8);
            acc0[rt] = __builtin_amdgcn_mfma_f32_16x16x32_bf16(a0, b0, acc0[rt], 0, 0, 0);
            acc1[rt] = __builtin_amdgcn_mfma_f32_16x16x32_bf16(a0, b1, acc1[rt], 0, 0, 0);
        }
        b0 = n0; b1 = n1;
    }

    // epilogue: + bias, ELU (fast exp), store. C/D: col=lane&15, row=quad*4+reg
    const int col0 = g0 * 16 + c, col1 = g1 * 16 + c;
    const float bv0 = bias[col0], bv1 = bias[col1];
#pragma unroll
    for (int rt = 0; rt < 4; ++rt) {
#pragma unroll
        for (int reg = 0; reg < 4; ++reg) {
            int grow = base + rt * 16 + quad * 4 + reg;
            if (grow < N) {
                float v0 = acc0[rt][reg] + bv0;
                float v1 = acc1[rt][reg] + bv1;
                out[(size_t)grow * 128 + col0] = (v0 > 0.f) ? v0 : __expf(v0) - 1.0f;
                out[(size_t)grow * 128 + col1] = (v1 > 0.f) ? v1 : __expf(v1) - 1.0f;
            }
        }
    }
}

// ---------------- degfix: compacted MFMA GEMM over deg==0 rows ----------------
// out[n] = elu(xb[n] @ Wg^T + b) for the ~N/33 compacted nodes. 16 rows/block; blocks
// past cnt early-exit on 2 loads. 8 MFMA/wave, K=128, B from packed Vpg (32 KB, L2).
// Overwrites gemm's (wrong-under-fold) values; same-stream order makes it final.
__global__ __launch_bounds__(256)
void degfix(const unsigned short* __restrict__ xb, const int* __restrict__ d0list,
            const int* __restrict__ d0cnt, const unsigned short* __restrict__ Vpg,
            const float* __restrict__ bias, float* __restrict__ out) {
    const int cnt = *d0cnt;
    const int base = blockIdx.x * 16;
    if (base >= cnt) return;
    __shared__ __align__(16) unsigned short As[16 * DAST];
    const int t = threadIdx.x, wv = t >> 6, lane = t & 63;
    const int c = lane & 15, quad = lane >> 4;

    {   // stage 16 compacted rows: thread t -> row t>>4, chunk t&15 (broadcast d0list reads)
        int row = t >> 4, ch = t & 15;
        int i = base + row; if (i > cnt - 1) i = cnt - 1;
        int node = d0list[i];
        uint4 val = *(const uint4*)(xb + (size_t)node * 128 + ch * 8);
        *(uint4*)(As + row * DAST + ch * 8) = val;
    }
    const int g0 = 2 * wv, g1 = 2 * wv + 1;
    const bf16x8* VB = (const bf16x8*)Vpg;
    bf16x8 b0 = VB[(g0 * 4) * 64 + lane];
    bf16x8 b1 = VB[(g1 * 4) * 64 + lane];
    __syncthreads();

    f32x4 acc0 = (f32x4){0.f,0.f,0.f,0.f};
    f32x4 acc1 = (f32x4){0.f,0.f,0.f,0.f};
#pragma unroll
    for (int s2 = 0; s2 < 4; ++s2) {
        int sn = (s2 + 1) & 3;
        bf16x8 n0 = VB[(g0 * 4 + sn) * 64 + lane];
        bf16x8 n1 = VB[(g1 * 4 + sn) * 64 + lane];
        bf16x8 a0 = *(const bf16x8*)(As + c * DAST + s2 * 32 + quad * 8);
        acc0 = __builtin_amdgcn_mfma_f32_16x16x32_bf16(a0, b0, acc0, 0, 0, 0);
        acc1 = __builtin_amdgcn_mfma_f32_16x16x32_bf16(a0, b1, acc1, 0, 0, 0);
        b0 = n0; b1 = n1;
    }

    const int col0 = g0 * 16 + c, col1 = g1 * 16 + c;
    const float bv0 = bias[col0], bv1 = bias[col1];
#pragma unroll
    for (int reg = 0; reg < 4; ++reg) {
        int i = base + quad * 4 + reg;
        if (i < cnt) {
            int n = d0list[i];
            float v0 = acc0[reg] + bv0;
            float v1 = acc1[reg] + bv1;
            out[(size_t)n * 128 + col0] = (v0 > 0.f) ? v0 : __expf(v0) - 1.0f;
            out[(size_t)n * 128 + col1] = (v1 > 0.f) ? v1 : __expf(v1) - 1.0f;
        }
    }
}

extern "C" void kernel_launch(void* const* d_in, const int* in_sizes, int n_in,
                              void* d_out, int out_size, void* d_ws, size_t ws_size,
                              hipStream_t stream) {
    const float* x  = (const float*)d_in[0];
    const float* Wg = (const float*)d_in[1];
    const float* Wl = (const float*)d_in[2];
    const float* Ws = (const float*)d_in[3];
    const float* b  = (const float*)d_in[4];
    const int*   src = (const int*)d_in[5];
    const int*   dst = (const int*)d_in[6];
    const int*   deg = (const int*)d_in[7];
    const int E = in_sizes[5];
    const int N = in_sizes[7];
    float* out = (float*)d_out;

    const size_t NB = (size_t)N * 128 * 2;                        // 12.8 MB
    unsigned short* Vp     = (unsigned short*)d_ws;               // 64 KB
    unsigned short* Vpg    = (unsigned short*)((char*)d_ws + 65536);      // 32 KB
    int*            blkoff = (int*)((char*)d_ws + 98304);         // 32 KB reserved
    int*            d0cnt  = (int*)((char*)d_ws + 131072);        // 256 B reserved
    int*            d0list = (int*)((char*)d_ws + 131328);        // 200 KB (N ints)
    unsigned short* xb     = (unsigned short*)((char*)d_ws + 335872);
    unsigned short* Mm     = (unsigned short*)((char*)d_ws + 335872 + NB);

    const int nblk_g = (N + GNPB - 1) / GNPB;      // 6250
    const int noffb  = (nblk_g + 255) / 256;       // 25
    const int ncmp   = (N + 255) / 256;            // 196
    const int total8 = N * 16;
    const int nconv  = (total8 + 255) / 256;       // 3125

    hipMemsetAsync(d0cnt, 0, sizeof(int), stream);
    prep<<<dim3(VP_BLOCKS + VPG_BLOCKS + noffb + ncmp + nconv), dim3(256), 0, stream>>>(
        x, Wg, Wl, Ws, dst, deg, Vp, Vpg, xb, blkoff, d0cnt, d0list,
        total8, nblk_g, noffb, ncmp, E, N);
    gather<<<dim3(nblk_g), dim3(512), 0, stream>>>(xb, src, deg, blkoff, Mm, N);
    gemm<<<dim3((N + MNPB - 1) / MNPB), dim3(256), 0, stream>>>(xb, Mm, Vp, b, out, N);
    degfix<<<dim3((N + 15) / 16), dim3(256), 0, stream>>>(xb, d0list, d0cnt, Vpg, b, out);
}

// Round 6
// 148.606 us; speedup vs baseline: 1.3735x; 1.0018x over previous
//
#include <hip/hip_runtime.h>
#include <cstdint>
#include <cstddef>

#define GNPB 8        // nodes per gather block (8 waves, 1 node/wave)
#define MNPB 16       // rows per gemm block (proven tile; 64-row variant cost occupancy+tail, R5)
#define GAST 264      // gemm LDS A row stride in elems (528 B) — breaks 512B-stride banks
#define DAST 136      // degfix LDS A row stride (K=128 + 8 pad)
#define VP_BLOCKS 16  // prep blocks packing Vp (4096 threads, K=256)
#define VPG_BLOCKS 8  // prep blocks packing Vpg (2048 threads, K=128, Wg only)

typedef __attribute__((ext_vector_type(8))) short bf16x8;
typedef __attribute__((ext_vector_type(4))) float f32x4;

static __device__ __forceinline__ unsigned short f2bf(float f) {
    unsigned int u = __builtin_bit_cast(unsigned int, f);
    u += 0x7fffu + ((u >> 16) & 1u);
    return (unsigned short)(u >> 16);
}
static __device__ __forceinline__ float bfhi(unsigned int u) { return __builtin_bit_cast(float, u & 0xFFFF0000u); }
static __device__ __forceinline__ float bflo(unsigned int u) { return __builtin_bit_cast(float, u << 16); }
// masked bf16x8 accumulate: m = all-ones keeps, 0 zeroes (bf16 0x0000 == +0.0)
static __device__ __forceinline__ void acc8(float* a, const uint4& v, unsigned m) {
    unsigned x0 = v.x & m, x1 = v.y & m, x2 = v.z & m, x3 = v.w & m;
    a[0] += bflo(x0); a[1] += bfhi(x0); a[2] += bflo(x1); a[3] += bfhi(x1);
    a[4] += bflo(x2); a[5] += bfhi(x2); a[6] += bflo(x3); a[7] += bfhi(x3);
}

// ---------------- Prep: Vp/Vpg pack, xb = bf16(x), blkoff, deg0 compaction ----------------
// Vp layout: element ((g*8 + s)*64 + lane)*8 + j = B1[g*16 + (lane&15)][s*32 + (lane>>4)*8 + j]
// (B1 = [Wg+Ws | Wl], K=256). Vpg: same pattern, 4 k-steps, Wg only (K=128).
__global__ __launch_bounds__(256)
void prep(const float* __restrict__ x, const float* __restrict__ Wg,
          const float* __restrict__ Wl, const float* __restrict__ Ws,
          const int* __restrict__ dst, const int* __restrict__ deg,
          unsigned short* __restrict__ Vp, unsigned short* __restrict__ Vpg,
          unsigned short* __restrict__ xb, int* __restrict__ blkoff,
          int* __restrict__ d0cnt, int* __restrict__ d0list,
          int total8, int nblk_g, int noffb, int ncmp, int E, int N) {
    const int bx = blockIdx.x, t = threadIdx.x;
    if (bx < VP_BLOCKS) {
        int gid = bx * 256 + t;
        if (gid < 4096) {
            int l = gid & 63, srow = (gid >> 6) & 7, g = gid >> 9;
            int o = g * 16 + (l & 15);
            int k = srow * 32 + (l >> 4) * 8;
            uint4 u;
            if (k < 128) {                     // first K-segment: W1 = Wg + Ws
                const float* pg = Wg + o * 128 + k;
                const float* ps = Ws + o * 128 + k;
                u.x = (unsigned)f2bf(pg[0]+ps[0]) | ((unsigned)f2bf(pg[1]+ps[1]) << 16);
                u.y = (unsigned)f2bf(pg[2]+ps[2]) | ((unsigned)f2bf(pg[3]+ps[3]) << 16);
                u.z = (unsigned)f2bf(pg[4]+ps[4]) | ((unsigned)f2bf(pg[5]+ps[5]) << 16);
                u.w = (unsigned)f2bf(pg[6]+ps[6]) | ((unsigned)f2bf(pg[7]+ps[7]) << 16);
            } else {                           // second K-segment: Wl
                const float* pl = Wl + o * 128 + (k - 128);
                u.x = (unsigned)f2bf(pl[0]) | ((unsigned)f2bf(pl[1]) << 16);
                u.y = (unsigned)f2bf(pl[2]) | ((unsigned)f2bf(pl[3]) << 16);
                u.z = (unsigned)f2bf(pl[4]) | ((unsigned)f2bf(pl[5]) << 16);
                u.w = (unsigned)f2bf(pl[6]) | ((unsigned)f2bf(pl[7]) << 16);
            }
            ((uint4*)Vp)[gid] = u;
        }
    } else if (bx < VP_BLOCKS + VPG_BLOCKS) {
        int gid = (bx - VP_BLOCKS) * 256 + t;  // 2048 entries: Wg-only panel, K=128
        if (gid < 2048) {
            int l = gid & 63, s = (gid >> 6) & 3, g = gid >> 8;
            int o = g * 16 + (l & 15);
            int k = s * 32 + (l >> 4) * 8;
            const float* p = Wg + o * 128 + k;
            uint4 u;
            u.x = (unsigned)f2bf(p[0]) | ((unsigned)f2bf(p[1]) << 16);
            u.y = (unsigned)f2bf(p[2]) | ((unsigned)f2bf(p[3]) << 16);
            u.z = (unsigned)f2bf(p[4]) | ((unsigned)f2bf(p[5]) << 16);
            u.w = (unsigned)f2bf(p[6]) | ((unsigned)f2bf(p[7]) << 16);
            ((uint4*)Vpg)[gid] = u;
        }
    } else if (bx < VP_BLOCKS + VPG_BLOCKS + noffb) {
        int b = (bx - VP_BLOCKS - VPG_BLOCKS) * 256 + t;
        if (b < nblk_g) {
            int target = b * GNPB;
            int lo = 0, hi = E;
            while (lo < hi) { int mid = (lo + hi) >> 1; if (dst[mid] < target) lo = mid + 1; else hi = mid; }
            blkoff[b] = lo;
        }
    } else if (bx < VP_BLOCKS + VPG_BLOCKS + noffb + ncmp) {
        int n = (bx - VP_BLOCKS - VPG_BLOCKS - noffb) * 256 + t;
        if (n < N && deg[n] == 0) {
            int i = atomicAdd(d0cnt, 1);       // device-scope; order irrelevant
            d0list[i] = n;
        }
    } else {
        int gid = (bx - VP_BLOCKS - VPG_BLOCKS - noffb - ncmp) * 256 + t;
        if (gid < total8) {
            const float4* px = (const float4*)x + (size_t)gid * 2;
            float4 a = px[0], bq = px[1];
            uint4 u;
            u.x = (unsigned)f2bf(a.x)  | ((unsigned)f2bf(a.y)  << 16);
            u.y = (unsigned)f2bf(a.z)  | ((unsigned)f2bf(a.w)  << 16);
            u.z = (unsigned)f2bf(bq.x) | ((unsigned)f2bf(bq.y) << 16);
            u.w = (unsigned)f2bf(bq.z) | ((unsigned)f2bf(bq.w) << 16);
            ((uint4*)xb)[gid] = u;
        }
    }
}

// ---------------- Gather: M[n] = (deg>0) ? mean_e xb[src[e]] : 0  (bf16) ----------------
// One node per wave, 8 waves/block, barrier-free. (proven kernel, unchanged)
__global__ __launch_bounds__(512, 7)
void gather(const unsigned short* __restrict__ xb, const int* __restrict__ src,
            const int* __restrict__ deg, const int* __restrict__ blkoff,
            unsigned short* __restrict__ M, int N) {
    const int t = threadIdx.x, wv = t >> 6, lane = t & 63;
    const int c = lane & 15, p = lane >> 4;
    const int base = blockIdx.x * GNPB;

    int dg8 = 0;
    if (lane < GNPB && base + lane < N) dg8 = deg[base + lane];
    int incl = dg8;
#pragma unroll
    for (int off = 1; off < GNPB; off <<= 1) {
        int v = __shfl_up(incl, off, 64);
        if (lane >= off) incl += v;
    }
    const int d = __shfl(dg8, wv, 64);
    const int s = blkoff[blockIdx.x] + __shfl(incl, wv, 64) - d;
    const int n = base + wv;
    if (n >= N) return;

    int idx = 0;
    if (lane < d) idx = src[s + lane];      // one coalesced shot, d <= 32

    const uint4* x4 = (const uint4*)xb;
    int r0 = __shfl(idx, p, 64),      r1 = __shfl(idx, p + 4, 64);
    int r2 = __shfl(idx, p + 8, 64),  r3 = __shfl(idx, p + 12, 64);
    uint4 v0 = x4[(size_t)r0 * 16 + c], v1 = x4[(size_t)r1 * 16 + c];
    uint4 v2 = x4[(size_t)r2 * 16 + c], v3 = x4[(size_t)r3 * 16 + c];
    uint4 v4, v5, v6, v7;
    const bool two = (d > 16);
    if (two) {                               // issue second batch BEFORE accumulating first
        int e = 16 + p;
        int r4 = __shfl(idx, e, 64),      r5 = __shfl(idx, e + 4, 64);
        int r6 = __shfl(idx, e + 8, 64),  r7 = __shfl(idx, e + 12, 64);
        v4 = x4[(size_t)r4 * 16 + c]; v5 = x4[(size_t)r5 * 16 + c];
        v6 = x4[(size_t)r6 * 16 + c]; v7 = x4[(size_t)r7 * 16 + c];
    }
    float a[8] = {0,0,0,0,0,0,0,0};
    float b[8] = {0,0,0,0,0,0,0,0};
    acc8(a, v0, (p      < d) ? ~0u : 0u);
    acc8(b, v1, (p + 4  < d) ? ~0u : 0u);
    acc8(a, v2, (p + 8  < d) ? ~0u : 0u);
    acc8(b, v3, (p + 12 < d) ? ~0u : 0u);
    if (two) {
        int e = 16 + p;
        acc8(a, v4, (e      < d) ? ~0u : 0u);
        acc8(b, v5, (e + 4  < d) ? ~0u : 0u);
        acc8(a, v6, (e + 8  < d) ? ~0u : 0u);
        acc8(b, v7, (e + 12 < d) ? ~0u : 0u);
    }
#pragma unroll
    for (int i = 0; i < 8; ++i) a[i] += b[i];
#pragma unroll
    for (int i = 0; i < 8; ++i) {
        a[i] += __shfl_xor(a[i], 16, 64);
        a[i] += __shfl_xor(a[i], 32, 64);
    }
    if (p == 0) {
        float inv = (d > 0) ? 1.0f / (float)d : 0.0f;
        uint4 u;
        u.x = (unsigned)f2bf(a[0]*inv) | ((unsigned)f2bf(a[1]*inv) << 16);
        u.y = (unsigned)f2bf(a[2]*inv) | ((unsigned)f2bf(a[3]*inv) << 16);
        u.z = (unsigned)f2bf(a[4]*inv) | ((unsigned)f2bf(a[5]*inv) << 16);
        u.w = (unsigned)f2bf(a[6]*inv) | ((unsigned)f2bf(a[7]*inv) << 16);
        ((uint4*)M)[(size_t)n * 16 + c] = u;
    }
}

// ---------------- GEMM: out = elu([xb | M] @ [Wg+Ws | Wl]^T + b), K=256 ----------------
// 16 rows/block, 3125 blocks, 256 threads (proven tile: 8.4 KB LDS -> high occupancy,
// ~8% tail quantization; the 64-row variant halved resident waves and cost ~9 µs, R5).
// A-panel staged once -> single barrier; B streamed from packed Vp with register
// prefetch; no barriers in the K-loop. Stores ALL rows; degfix overwrites deg==0 after.
__global__ __launch_bounds__(256)
void gemm(const unsigned short* __restrict__ xb, const unsigned short* __restrict__ Mm,
          const unsigned short* __restrict__ Vp, const float* __restrict__ bias,
          float* __restrict__ out, int N) {
    __shared__ __align__(16) unsigned short As[MNPB * GAST];
    const int t = threadIdx.x, wv = t >> 6, lane = t & 63;
    const int c = lane & 15, quad = lane >> 4;
    const int base = blockIdx.x * MNPB;

#pragma unroll
    for (int it = 0; it < 2; ++it) {
        int f = it * 256 + t;
        int row = f >> 5, ch = f & 31;
        int grow = base + row; if (grow > N - 1) grow = N - 1;
        const unsigned short* gp = (ch < 16)
            ? xb + (size_t)grow * 128 + ch * 8
            : Mm + (size_t)grow * 128 + (ch - 16) * 8;
        uint4 val = *(const uint4*)gp;
        *(uint4*)(As + row * GAST + ch * 8) = val;
    }
    const int g0 = 2 * wv, g1 = 2 * wv + 1;
    const bf16x8* VB = (const bf16x8*)Vp;
    bf16x8 b0 = VB[(g0 * 8) * 64 + lane];       // B prefetch before the barrier
    bf16x8 b1 = VB[(g1 * 8) * 64 + lane];
    __syncthreads();

    f32x4 acc0 = (f32x4){0.f, 0.f, 0.f, 0.f};
    f32x4 acc1 = (f32x4){0.f, 0.f, 0.f, 0.f};
#pragma unroll
    for (int s2 = 0; s2 < 8; ++s2) {
        int sn = (s2 + 1) & 7;                  // branchless prefetch
        bf16x8 n0 = VB[(g0 * 8 + sn) * 64 + lane];
        bf16x8 n1 = VB[(g1 * 8 + sn) * 64 + lane];
        bf16x8 a0 = *(const bf16x8*)(As + c * GAST + s2 * 32 + quad * 8);
        acc0 = __builtin_amdgcn_mfma_f32_16x16x32_bf16(a0, b0, acc0, 0, 0, 0);
        acc1 = __builtin_amdgcn_mfma_f32_16x16x32_bf16(a0, b1, acc1, 0, 0, 0);
        b0 = n0; b1 = n1;
    }

    // epilogue: + bias, ELU (fast exp), store. C/D: col=lane&15, row=quad*4+reg
    const int col0 = g0 * 16 + c, col1 = g1 * 16 + c;
    const float bv0 = bias[col0], bv1 = bias[col1];
#pragma unroll
    for (int reg = 0; reg < 4; ++reg) {
        int grow = base + quad * 4 + reg;
        if (grow < N) {
            float v0 = acc0[reg] + bv0;
            float v1 = acc1[reg] + bv1;
            out[(size_t)grow * 128 + col0] = (v0 > 0.f) ? v0 : __expf(v0) - 1.0f;
            out[(size_t)grow * 128 + col1] = (v1 > 0.f) ? v1 : __expf(v1) - 1.0f;
        }
    }
}

// ---------------- degfix: compacted MFMA GEMM over deg==0 rows ----------------
// out[n] = elu(xb[n] @ Wg^T + b) for the ~N/33 compacted nodes. 16 rows/block; blocks
// past cnt early-exit on 2 loads. 8 MFMA/wave, K=128, B from packed Vpg (32 KB, L2).
// Overwrites gemm's (wrong-under-fold) values; same-stream order makes it final.
__global__ __launch_bounds__(256)
void degfix(const unsigned short* __restrict__ xb, const int* __restrict__ d0list,
            const int* __restrict__ d0cnt, const unsigned short* __restrict__ Vpg,
            const float* __restrict__ bias, float* __restrict__ out) {
    const int cnt = *d0cnt;
    const int base = blockIdx.x * 16;
    if (base >= cnt) return;
    __shared__ __align__(16) unsigned short As[16 * DAST];
    const int t = threadIdx.x, wv = t >> 6, lane = t & 63;
    const int c = lane & 15, quad = lane >> 4;

    {   // stage 16 compacted rows: thread t -> row t>>4, chunk t&15 (broadcast d0list reads)
        int row = t >> 4, ch = t & 15;
        int i = base + row; if (i > cnt - 1) i = cnt - 1;
        int node = d0list[i];
        uint4 val = *(const uint4*)(xb + (size_t)node * 128 + ch * 8);
        *(uint4*)(As + row * DAST + ch * 8) = val;
    }
    const int g0 = 2 * wv, g1 = 2 * wv + 1;
    const bf16x8* VB = (const bf16x8*)Vpg;
    bf16x8 b0 = VB[(g0 * 4) * 64 + lane];
    bf16x8 b1 = VB[(g1 * 4) * 64 + lane];
    __syncthreads();

    f32x4 acc0 = (f32x4){0.f,0.f,0.f,0.f};
    f32x4 acc1 = (f32x4){0.f,0.f,0.f,0.f};
#pragma unroll
    for (int s2 = 0; s2 < 4; ++s2) {
        int sn = (s2 + 1) & 3;
        bf16x8 n0 = VB[(g0 * 4 + sn) * 64 + lane];
        bf16x8 n1 = VB[(g1 * 4 + sn) * 64 + lane];
        bf16x8 a0 = *(const bf16x8*)(As + c * DAST + s2 * 32 + quad * 8);
        acc0 = __builtin_amdgcn_mfma_f32_16x16x32_bf16(a0, b0, acc0, 0, 0, 0);
        acc1 = __builtin_amdgcn_mfma_f32_16x16x32_bf16(a0, b1, acc1, 0, 0, 0);
        b0 = n0; b1 = n1;
    }

    const int col0 = g0 * 16 + c, col1 = g1 * 16 + c;
    const float bv0 = bias[col0], bv1 = bias[col1];
#pragma unroll
    for (int reg = 0; reg < 4; ++reg) {
        int i = base + quad * 4 + reg;
        if (i < cnt) {
            int n = d0list[i];
            float v0 = acc0[reg] + bv0;
            float v1 = acc1[reg] + bv1;
            out[(size_t)n * 128 + col0] = (v0 > 0.f) ? v0 : __expf(v0) - 1.0f;
            out[(size_t)n * 128 + col1] = (v1 > 0.f) ? v1 : __expf(v1) - 1.0f;
        }
    }
}

extern "C" void kernel_launch(void* const* d_in, const int* in_sizes, int n_in,
                              void* d_out, int out_size, void* d_ws, size_t ws_size,
                              hipStream_t stream) {
    const float* x  = (const float*)d_in[0];
    const float* Wg = (const float*)d_in[1];
    const float* Wl = (const float*)d_in[2];
    const float* Ws = (const float*)d_in[3];
    const float* b  = (const float*)d_in[4];
    const int*   src = (const int*)d_in[5];
    const int*   dst = (const int*)d_in[6];
    const int*   deg = (const int*)d_in[7];
    const int E = in_sizes[5];
    const int N = in_sizes[7];
    float* out = (float*)d_out;

    const size_t NB = (size_t)N * 128 * 2;                        // 12.8 MB
    unsigned short* Vp     = (unsigned short*)d_ws;               // 64 KB
    unsigned short* Vpg    = (unsigned short*)((char*)d_ws + 65536);      // 32 KB
    int*            blkoff = (int*)((char*)d_ws + 98304);         // 32 KB reserved
    int*            d0cnt  = (int*)((char*)d_ws + 131072);        // 256 B reserved
    int*            d0list = (int*)((char*)d_ws + 131328);        // 200 KB (N ints)
    unsigned short* xb     = (unsigned short*)((char*)d_ws + 335872);
    unsigned short* Mm     = (unsigned short*)((char*)d_ws + 335872 + NB);

    const int nblk_g = (N + GNPB - 1) / GNPB;      // 6250
    const int noffb  = (nblk_g + 255) / 256;       // 25
    const int ncmp   = (N + 255) / 256;            // 196
    const int total8 = N * 16;
    const int nconv  = (total8 + 255) / 256;       // 3125

    hipMemsetAsync(d0cnt, 0, sizeof(int), stream);
    prep<<<dim3(VP_BLOCKS + VPG_BLOCKS + noffb + ncmp + nconv), dim3(256), 0, stream>>>(
        x, Wg, Wl, Ws, dst, deg, Vp, Vpg, xb, blkoff, d0cnt, d0list,
        total8, nblk_g, noffb, ncmp, E, N);
    gather<<<dim3(nblk_g), dim3(512), 0, stream>>>(xb, src, deg, blkoff, Mm, N);
    gemm<<<dim3((N + MNPB - 1) / MNPB), dim3(256), 0, stream>>>(xb, Mm, Vp, b, out, N);
    degfix<<<dim3((N + 15) / 16), dim3(256), 0, stream>>>(xb, d0list, d0cnt, Vpg, b, out);
}

// Round 7
// 137.922 us; speedup vs baseline: 1.4800x; 1.0775x over previous
//
#include <hip/hip_runtime.h>
#include <cstdint>
#include <cstddef>

#define GNPB 8        // nodes per gather block (8 waves, 1 node/wave)
#define MNPB 16       // rows per gemm block (proven tile)
#define GAST 264      // gemm LDS A row stride in elems (528 B) — breaks 512B-stride banks
#define DFRNG 512     // nodes scanned per degfix block
#define VP_BLOCKS 16  // prep blocks packing Vp (4096 threads, K=256)
#define VPG_BLOCKS 8  // prep blocks packing Vpg (2048 threads, K=128, Wg only)

typedef __attribute__((ext_vector_type(8))) short bf16x8;
typedef __attribute__((ext_vector_type(4))) float f32x4;

static __device__ __forceinline__ unsigned short f2bf(float f) {
    unsigned int u = __builtin_bit_cast(unsigned int, f);
    u += 0x7fffu + ((u >> 16) & 1u);
    return (unsigned short)(u >> 16);
}
static __device__ __forceinline__ float bfhi(unsigned int u) { return __builtin_bit_cast(float, u & 0xFFFF0000u); }
static __device__ __forceinline__ float bflo(unsigned int u) { return __builtin_bit_cast(float, u << 16); }
// masked bf16x8 accumulate: m = all-ones keeps, 0 zeroes (bf16 0x0000 == +0.0)
static __device__ __forceinline__ void acc8(float* a, const uint4& v, unsigned m) {
    unsigned x0 = v.x & m, x1 = v.y & m, x2 = v.z & m, x3 = v.w & m;
    a[0] += bflo(x0); a[1] += bfhi(x0); a[2] += bflo(x1); a[3] += bfhi(x1);
    a[4] += bflo(x2); a[5] += bfhi(x2); a[6] += bflo(x3); a[7] += bfhi(x3);
}

// ---------------- Prep: Vp/Vpg pack, xb = bf16(x), blkoff ----------------
// Vp layout: element ((g*8 + s)*64 + lane)*8 + j = B1[g*16 + (lane&15)][s*32 + (lane>>4)*8 + j]
// (B1 = [Wg+Ws | Wl], K=256). Vpg: same pattern, 4 k-steps, Wg only (K=128).
__global__ __launch_bounds__(256)
void prep(const float* __restrict__ x, const float* __restrict__ Wg,
          const float* __restrict__ Wl, const float* __restrict__ Ws,
          const int* __restrict__ dst,
          unsigned short* __restrict__ Vp, unsigned short* __restrict__ Vpg,
          unsigned short* __restrict__ xb, int* __restrict__ blkoff,
          int total8, int nblk_g, int noffb, int E) {
    const int bx = blockIdx.x, t = threadIdx.x;
    if (bx < VP_BLOCKS) {
        int gid = bx * 256 + t;
        if (gid < 4096) {
            int l = gid & 63, srow = (gid >> 6) & 7, g = gid >> 9;
            int o = g * 16 + (l & 15);
            int k = srow * 32 + (l >> 4) * 8;
            uint4 u;
            if (k < 128) {                     // first K-segment: W1 = Wg + Ws
                const float* pg = Wg + o * 128 + k;
                const float* ps = Ws + o * 128 + k;
                u.x = (unsigned)f2bf(pg[0]+ps[0]) | ((unsigned)f2bf(pg[1]+ps[1]) << 16);
                u.y = (unsigned)f2bf(pg[2]+ps[2]) | ((unsigned)f2bf(pg[3]+ps[3]) << 16);
                u.z = (unsigned)f2bf(pg[4]+ps[4]) | ((unsigned)f2bf(pg[5]+ps[5]) << 16);
                u.w = (unsigned)f2bf(pg[6]+ps[6]) | ((unsigned)f2bf(pg[7]+ps[7]) << 16);
            } else {                           // second K-segment: Wl
                const float* pl = Wl + o * 128 + (k - 128);
                u.x = (unsigned)f2bf(pl[0]) | ((unsigned)f2bf(pl[1]) << 16);
                u.y = (unsigned)f2bf(pl[2]) | ((unsigned)f2bf(pl[3]) << 16);
                u.z = (unsigned)f2bf(pl[4]) | ((unsigned)f2bf(pl[5]) << 16);
                u.w = (unsigned)f2bf(pl[6]) | ((unsigned)f2bf(pl[7]) << 16);
            }
            ((uint4*)Vp)[gid] = u;
        }
    } else if (bx < VP_BLOCKS + VPG_BLOCKS) {
        int gid = (bx - VP_BLOCKS) * 256 + t;  // 2048 entries: Wg-only panel, K=128
        if (gid < 2048) {
            int l = gid & 63, s = (gid >> 6) & 3, g = gid >> 8;
            int o = g * 16 + (l & 15);
            int k = s * 32 + (l >> 4) * 8;
            const float* p = Wg + o * 128 + k;
            uint4 u;
            u.x = (unsigned)f2bf(p[0]) | ((unsigned)f2bf(p[1]) << 16);
            u.y = (unsigned)f2bf(p[2]) | ((unsigned)f2bf(p[3]) << 16);
            u.z = (unsigned)f2bf(p[4]) | ((unsigned)f2bf(p[5]) << 16);
            u.w = (unsigned)f2bf(p[6]) | ((unsigned)f2bf(p[7]) << 16);
            ((uint4*)Vpg)[gid] = u;
        }
    } else if (bx < VP_BLOCKS + VPG_BLOCKS + noffb) {
        int b = (bx - VP_BLOCKS - VPG_BLOCKS) * 256 + t;
        if (b < nblk_g) {
            int target = b * GNPB;
            int lo = 0, hi = E;
            while (lo < hi) { int mid = (lo + hi) >> 1; if (dst[mid] < target) lo = mid + 1; else hi = mid; }
            blkoff[b] = lo;
        }
    } else {
        int gid = (bx - VP_BLOCKS - VPG_BLOCKS - noffb) * 256 + t;
        if (gid < total8) {
            const float4* px = (const float4*)x + (size_t)gid * 2;
            float4 a = px[0], bq = px[1];
            uint4 u;
            u.x = (unsigned)f2bf(a.x)  | ((unsigned)f2bf(a.y)  << 16);
            u.y = (unsigned)f2bf(a.z)  | ((unsigned)f2bf(a.w)  << 16);
            u.z = (unsigned)f2bf(bq.x) | ((unsigned)f2bf(bq.y) << 16);
            u.w = (unsigned)f2bf(bq.z) | ((unsigned)f2bf(bq.w) << 16);
            ((uint4*)xb)[gid] = u;
        }
    }
}

// ---------------- Gather: M[n] = (deg>0) ? mean_e xb[src[e]] : 0  (bf16) ----------------
// One node per wave, 8 waves/block, barrier-free. (proven kernel, unchanged)
__global__ __launch_bounds__(512, 7)
void gather(const unsigned short* __restrict__ xb, const int* __restrict__ src,
            const int* __restrict__ deg, const int* __restrict__ blkoff,
            unsigned short* __restrict__ M, int N) {
    const int t = threadIdx.x, wv = t >> 6, lane = t & 63;
    const int c = lane & 15, p = lane >> 4;
    const int base = blockIdx.x * GNPB;

    int dg8 = 0;
    if (lane < GNPB && base + lane < N) dg8 = deg[base + lane];
    int incl = dg8;
#pragma unroll
    for (int off = 1; off < GNPB; off <<= 1) {
        int v = __shfl_up(incl, off, 64);
        if (lane >= off) incl += v;
    }
    const int d = __shfl(dg8, wv, 64);
    const int s = blkoff[blockIdx.x] + __shfl(incl, wv, 64) - d;
    const int n = base + wv;
    if (n >= N) return;

    int idx = 0;
    if (lane < d) idx = src[s + lane];      // one coalesced shot, d <= 32

    const uint4* x4 = (const uint4*)xb;
    int r0 = __shfl(idx, p, 64),      r1 = __shfl(idx, p + 4, 64);
    int r2 = __shfl(idx, p + 8, 64),  r3 = __shfl(idx, p + 12, 64);
    uint4 v0 = x4[(size_t)r0 * 16 + c], v1 = x4[(size_t)r1 * 16 + c];
    uint4 v2 = x4[(size_t)r2 * 16 + c], v3 = x4[(size_t)r3 * 16 + c];
    uint4 v4, v5, v6, v7;
    const bool two = (d > 16);
    if (two) {                               // issue second batch BEFORE accumulating first
        int e = 16 + p;
        int r4 = __shfl(idx, e, 64),      r5 = __shfl(idx, e + 4, 64);
        int r6 = __shfl(idx, e + 8, 64),  r7 = __shfl(idx, e + 12, 64);
        v4 = x4[(size_t)r4 * 16 + c]; v5 = x4[(size_t)r5 * 16 + c];
        v6 = x4[(size_t)r6 * 16 + c]; v7 = x4[(size_t)r7 * 16 + c];
    }
    float a[8] = {0,0,0,0,0,0,0,0};
    float b[8] = {0,0,0,0,0,0,0,0};
    acc8(a, v0, (p      < d) ? ~0u : 0u);
    acc8(b, v1, (p + 4  < d) ? ~0u : 0u);
    acc8(a, v2, (p + 8  < d) ? ~0u : 0u);
    acc8(b, v3, (p + 12 < d) ? ~0u : 0u);
    if (two) {
        int e = 16 + p;
        acc8(a, v4, (e      < d) ? ~0u : 0u);
        acc8(b, v5, (e + 4  < d) ? ~0u : 0u);
        acc8(a, v6, (e + 8  < d) ? ~0u : 0u);
        acc8(b, v7, (e + 12 < d) ? ~0u : 0u);
    }
#pragma unroll
    for (int i = 0; i < 8; ++i) a[i] += b[i];
#pragma unroll
    for (int i = 0; i < 8; ++i) {
        a[i] += __shfl_xor(a[i], 16, 64);
        a[i] += __shfl_xor(a[i], 32, 64);
    }
    if (p == 0) {
        float inv = (d > 0) ? 1.0f / (float)d : 0.0f;
        uint4 u;
        u.x = (unsigned)f2bf(a[0]*inv) | ((unsigned)f2bf(a[1]*inv) << 16);
        u.y = (unsigned)f2bf(a[2]*inv) | ((unsigned)f2bf(a[3]*inv) << 16);
        u.z = (unsigned)f2bf(a[4]*inv) | ((unsigned)f2bf(a[5]*inv) << 16);
        u.w = (unsigned)f2bf(a[6]*inv) | ((unsigned)f2bf(a[7]*inv) << 16);
        ((uint4*)M)[(size_t)n * 16 + c] = u;
    }
}

// ---------------- GEMM + merged degfix (one dispatch) ----------------
// Blocks [0, ngemm): out = elu([xb | M] @ [Wg+Ws | Wl]^T + b), K=256, 16 rows/block,
//   proven structure; deg==0 rows SKIPPED (srowok) so repair blocks own them (disjoint
//   writes -> race-free within one launch, no ordering needed).
// Blocks [ngemm, ngemm+ndeg): repair — scan a 512-node range for deg==0, compact ids
//   into LDS (no global counter/memset/extra dispatch), then K=128 MFMA tiles vs Vpg:
//   out[n] = elu(xb[n] @ Wg^T + b).
__global__ __launch_bounds__(256)
void gemm(const unsigned short* __restrict__ xb, const unsigned short* __restrict__ Mm,
          const int* __restrict__ deg, const unsigned short* __restrict__ Vp,
          const unsigned short* __restrict__ Vpg, const float* __restrict__ bias,
          float* __restrict__ out, int N, int ngemm) {
    __shared__ __align__(16) unsigned short As[MNPB * GAST];
    const int t = threadIdx.x, wv = t >> 6, lane = t & 63;
    const int c = lane & 15, quad = lane >> 4;
    const int g0 = 2 * wv, g1 = 2 * wv + 1;
    const int col0 = g0 * 16 + c, col1 = g1 * 16 + c;
    const float bv0 = bias[col0], bv1 = bias[col1];

    if (blockIdx.x >= ngemm) {
        // ---------- repair path ----------
        __shared__ int nds[DFRNG];
        __shared__ int ncnt;
        const int rb = (blockIdx.x - ngemm) * DFRNG;
        if (t == 0) ncnt = 0;
        __syncthreads();
#pragma unroll
        for (int i = 0; i < DFRNG / 256; ++i) {
            int n = rb + i * 256 + t;
            if (n < N && deg[n] == 0) nds[atomicAdd(&ncnt, 1)] = n;
        }
        __syncthreads();
        const int cnt = ncnt;
        if (cnt == 0) return;
        const bf16x8* VB = (const bf16x8*)Vpg;
        for (int base = 0; base < cnt; base += 16) {
            {   // stage 16 compacted rows: thread t -> row t>>4, chunk t&15
                int row = t >> 4, ch = t & 15;
                int i = base + row; if (i > cnt - 1) i = cnt - 1;
                int node = nds[i];
                uint4 val = *(const uint4*)(xb + (size_t)node * 128 + ch * 8);
                *(uint4*)(As + row * GAST + ch * 8) = val;
            }
            bf16x8 b0 = VB[(g0 * 4) * 64 + lane];
            bf16x8 b1 = VB[(g1 * 4) * 64 + lane];
            __syncthreads();
            f32x4 acc0 = (f32x4){0.f,0.f,0.f,0.f};
            f32x4 acc1 = (f32x4){0.f,0.f,0.f,0.f};
#pragma unroll
            for (int s2 = 0; s2 < 4; ++s2) {
                int sn = (s2 + 1) & 3;
                bf16x8 n0 = VB[(g0 * 4 + sn) * 64 + lane];
                bf16x8 n1 = VB[(g1 * 4 + sn) * 64 + lane];
                bf16x8 a0 = *(const bf16x8*)(As + c * GAST + s2 * 32 + quad * 8);
                acc0 = __builtin_amdgcn_mfma_f32_16x16x32_bf16(a0, b0, acc0, 0, 0, 0);
                acc1 = __builtin_amdgcn_mfma_f32_16x16x32_bf16(a0, b1, acc1, 0, 0, 0);
                b0 = n0; b1 = n1;
            }
#pragma unroll
            for (int reg = 0; reg < 4; ++reg) {
                int i = base + quad * 4 + reg;
                if (i < cnt) {
                    int n = nds[i];
                    float v0 = acc0[reg] + bv0;
                    float v1 = acc1[reg] + bv1;
                    out[(size_t)n * 128 + col0] = (v0 > 0.f) ? v0 : __expf(v0) - 1.0f;
                    out[(size_t)n * 128 + col1] = (v1 > 0.f) ? v1 : __expf(v1) - 1.0f;
                }
            }
            __syncthreads();   // As reused next tile
        }
        return;
    }

    // ---------- main gemm path (proven 16-row tile) ----------
    __shared__ unsigned char srowok[MNPB];
    const int base = blockIdx.x * MNPB;
    if (t < MNPB) srowok[t] = (base + t < N && deg[base + t] > 0) ? 1 : 0;
#pragma unroll
    for (int it = 0; it < 2; ++it) {
        int f = it * 256 + t;
        int row = f >> 5, ch = f & 31;
        int grow = base + row; if (grow > N - 1) grow = N - 1;
        const unsigned short* gp = (ch < 16)
            ? xb + (size_t)grow * 128 + ch * 8
            : Mm + (size_t)grow * 128 + (ch - 16) * 8;
        uint4 val = *(const uint4*)gp;
        *(uint4*)(As + row * GAST + ch * 8) = val;
    }
    const bf16x8* VB = (const bf16x8*)Vp;
    bf16x8 b0 = VB[(g0 * 8) * 64 + lane];       // B prefetch before the barrier
    bf16x8 b1 = VB[(g1 * 8) * 64 + lane];
    __syncthreads();

    f32x4 acc0 = (f32x4){0.f, 0.f, 0.f, 0.f};
    f32x4 acc1 = (f32x4){0.f, 0.f, 0.f, 0.f};
#pragma unroll
    for (int s2 = 0; s2 < 8; ++s2) {
        int sn = (s2 + 1) & 7;                  // branchless prefetch
        bf16x8 n0 = VB[(g0 * 8 + sn) * 64 + lane];
        bf16x8 n1 = VB[(g1 * 8 + sn) * 64 + lane];
        bf16x8 a0 = *(const bf16x8*)(As + c * GAST + s2 * 32 + quad * 8);
        acc0 = __builtin_amdgcn_mfma_f32_16x16x32_bf16(a0, b0, acc0, 0, 0, 0);
        acc1 = __builtin_amdgcn_mfma_f32_16x16x32_bf16(a0, b1, acc1, 0, 0, 0);
        b0 = n0; b1 = n1;
    }

    // epilogue: + bias, ELU (fast exp), store. C/D: col=lane&15, row=quad*4+reg
#pragma unroll
    for (int reg = 0; reg < 4; ++reg) {
        int lrow = quad * 4 + reg;
        int grow = base + lrow;
        if (grow < N && srowok[lrow]) {
            float v0 = acc0[reg] + bv0;
            float v1 = acc1[reg] + bv1;
            out[(size_t)grow * 128 + col0] = (v0 > 0.f) ? v0 : __expf(v0) - 1.0f;
            out[(size_t)grow * 128 + col1] = (v1 > 0.f) ? v1 : __expf(v1) - 1.0f;
        }
    }
}

extern "C" void kernel_launch(void* const* d_in, const int* in_sizes, int n_in,
                              void* d_out, int out_size, void* d_ws, size_t ws_size,
                              hipStream_t stream) {
    const float* x  = (const float*)d_in[0];
    const float* Wg = (const float*)d_in[1];
    const float* Wl = (const float*)d_in[2];
    const float* Ws = (const float*)d_in[3];
    const float* b  = (const float*)d_in[4];
    const int*   src = (const int*)d_in[5];
    const int*   dst = (const int*)d_in[6];
    const int*   deg = (const int*)d_in[7];
    const int E = in_sizes[5];
    const int N = in_sizes[7];
    float* out = (float*)d_out;

    const size_t NB = (size_t)N * 128 * 2;                        // 12.8 MB
    unsigned short* Vp     = (unsigned short*)d_ws;               // 64 KB
    unsigned short* Vpg    = (unsigned short*)((char*)d_ws + 65536);      // 32 KB
    int*            blkoff = (int*)((char*)d_ws + 98304);         // 32 KB reserved
    unsigned short* xb     = (unsigned short*)((char*)d_ws + 131072);
    unsigned short* Mm     = (unsigned short*)((char*)d_ws + 131072 + NB);

    const int nblk_g = (N + GNPB - 1) / GNPB;      // 6250
    const int noffb  = (nblk_g + 255) / 256;       // 25
    const int total8 = N * 16;
    const int nconv  = (total8 + 255) / 256;       // 3125
    const int ngemm  = (N + MNPB - 1) / MNPB;      // 3125
    const int ndeg   = (N + DFRNG - 1) / DFRNG;    // 98

    prep<<<dim3(VP_BLOCKS + VPG_BLOCKS + noffb + nconv), dim3(256), 0, stream>>>(
        x, Wg, Wl, Ws, dst, Vp, Vpg, xb, blkoff, total8, nblk_g, noffb, E);
    gather<<<dim3(nblk_g), dim3(512), 0, stream>>>(xb, src, deg, blkoff, Mm, N);
    gemm<<<dim3(ngemm + ndeg), dim3(256), 0, stream>>>(xb, Mm, deg, Vp, Vpg, b, out, N, ngemm);
}